// Round 11
// baseline (260.986 us; speedup 1.0000x reference)
//
#include <hip/hip_runtime.h>
#include <math.h>

// MultiHeadAttention: B=2,S=2048,E=1024,H=16,DH=64,A=1024. fp32 in/out.
// Round 11: exact R8 base (197.7us best) + attention rewritten to load K/V
// B-fragments DIRECTLY from global in MFMA layout (QK B-frag = 16B row chunk
// of K; PV B-frag = 16B row chunk of vt). Ks/Vt LDS staging deleted -> zero
// barriers in the K-loop (Pb is wave-private), waves free-run; single-buffer
// register prefetch of next tile's frags. R10's LDS-transpose epilogue
// reverted (scattered global stores are cheap; LDS+barriers were not).
// d_ws (bf16 elems): xb[4Mi] qb[4Mi] kb[4Mi] vtb[4Mi] cc[4Mi] Wt[3Mi] Wot[1Mi]

namespace {
constexpr int kBn = 2, kS = 2048, kE = 1024, kH = 16, kDH = 64, kA = 1024;

typedef __attribute__((ext_vector_type(8))) short short8;
typedef __attribute__((ext_vector_type(4))) float f32x4;

// q pre-scale: (1/sqrt(DH)) * log2(e) so attention uses raw v_exp_f32.
#define QSCALE 0.18033688011112042f

__device__ inline unsigned short f2bf(float f) {
  union { float f; unsigned u; } x; x.f = f;
  unsigned r = x.u + 0x7fffu + ((x.u >> 16) & 1u);   // RNE
  return (unsigned short)(r >> 16);
}

__device__ inline void gld16(const void* g, void* l) {
  __builtin_amdgcn_global_load_lds(
      (const __attribute__((address_space(1))) unsigned int*)g,
      (__attribute__((address_space(3))) unsigned int*)l, 16, 0, 0);
}

// ---------------- cast x: fp32 -> bf16, elementwise ----------------------
__global__ __launch_bounds__(256) void cast_x_kernel(
    const float* __restrict__ x, unsigned short* __restrict__ xb) {
  const int i = (blockIdx.x * 256 + threadIdx.x) * 8;
  float4 a = *(const float4*)(x + i);
  float4 b = *(const float4*)(x + i + 4);
  unsigned short t[8];
  t[0] = f2bf(a.x); t[1] = f2bf(a.y); t[2] = f2bf(a.z); t[3] = f2bf(a.w);
  t[4] = f2bf(b.x); t[5] = f2bf(b.y); t[6] = f2bf(b.z); t[7] = f2bf(b.w);
  *(short8*)(xb + i) = *(const short8*)t;
}

// ---------------- cast+transpose Wq/Wk/Wv: [H,E,DH] -> [sel][h*64+d][e] --
__global__ __launch_bounds__(256) void cast_wqkv_kernel(
    const float* __restrict__ Wq, const float* __restrict__ Wk,
    const float* __restrict__ Wv, unsigned short* __restrict__ Wt) {
  const int sel = blockIdx.z;
  const float* __restrict__ W = (sel == 0) ? Wq : (sel == 1) ? Wk : Wv;
  const int h = blockIdx.y;
  const int e0 = blockIdx.x * 64;
  const int tid = threadIdx.x;

  __shared__ float T[64][68];
  const int el = tid >> 2, dq = tid & 3;
  const float* src = W + ((size_t)h * kE + e0 + el) * kDH + dq * 16;
#pragma unroll
  for (int j = 0; j < 4; ++j)
    *(float4*)&T[el][dq * 16 + j * 4] = *(const float4*)(src + j * 4);
  __syncthreads();

  const int d = tid & 63, w = tid >> 6;
  unsigned short t[16];
#pragma unroll
  for (int j = 0; j < 16; ++j) t[j] = f2bf(T[w * 16 + j][d]);
  unsigned short* dst =
      Wt + (((size_t)sel << 20) | ((size_t)(h * 64 + d) << 10)) + e0 + w * 16;
  *(short8*)dst = *(const short8*)&t[0];
  *(short8*)(dst + 8) = *(const short8*)&t[8];
}

// ---------------- cast+transpose Wo: [A,E] -> [e][a] ---------------------
__global__ __launch_bounds__(256) void cast_wo_kernel(
    const float* __restrict__ Wo, unsigned short* __restrict__ Wot) {
  const int a0 = blockIdx.x * 64, e0 = blockIdx.y * 64;
  const int tid = threadIdx.x;

  __shared__ float T[64][68];
  const int al = tid >> 2, dq = tid & 3;
  const float* src = Wo + (size_t)(a0 + al) * kE + e0 + dq * 16;
#pragma unroll
  for (int j = 0; j < 4; ++j)
    *(float4*)&T[al][dq * 16 + j * 4] = *(const float4*)(src + j * 4);
  __syncthreads();

  const int e = tid & 63, w = tid >> 6;
  unsigned short t[16];
#pragma unroll
  for (int j = 0; j < 16; ++j) t[j] = f2bf(T[w * 16 + j][e]);
  unsigned short* dst = Wot + ((size_t)(e0 + e) << 10) + a0 + w * 16;
  *(short8*)dst = *(const short8*)&t[0];
  *(short8*)(dst + 8) = *(const short8*)&t[8];
}

// ---------------- QKV GEMM (modes 0/1/2 over blockIdx.z) -----------------
// m97 structure (global_load_lds + __syncthreads; proven best at 3 blk/CU).
__global__ __launch_bounds__(256) void gemm_bf16_kernel(
    const unsigned short* __restrict__ A, const unsigned short* __restrict__ Bt,
    const float* __restrict__ b0, const float* __restrict__ b1,
    const float* __restrict__ b2,
    unsigned short* __restrict__ oq, unsigned short* __restrict__ okk,
    unsigned short* __restrict__ ov) {
  constexpr int K = 1024;
  const int mode = (int)blockIdx.z;
  const unsigned short* Bm = Bt + ((size_t)blockIdx.z << 20);
  const float* bias = (mode == 1) ? b1 : (mode == 2) ? b2 : b0;

  const int mt = blockIdx.x, nt = blockIdx.y;
  const int tid = threadIdx.x;
  const int wv = tid >> 6, lane = tid & 63, lq = lane & 15, quad = lane >> 4;
  const int wm = wv >> 1, wn = wv & 1;

  __shared__ unsigned short lA[128 * 32];
  __shared__ unsigned short lB[128 * 32];

  const int c0 = wv * 64 + lane;
  const int c1 = c0 + 256;
  const unsigned short* gA0 = A + (size_t)(mt * 128 + (c0 >> 2)) * K + (c0 & 3) * 8;
  const unsigned short* gA1 = A + (size_t)(mt * 128 + (c1 >> 2)) * K + (c1 & 3) * 8;
  const unsigned short* gB0 = Bm + (size_t)(nt * 128 + (c0 >> 2)) * K + (c0 & 3) * 8;
  const unsigned short* gB1 = Bm + (size_t)(nt * 128 + (c1 >> 2)) * K + (c1 & 3) * 8;
  unsigned short* lA0 = lA + (size_t)(wv * 64) * 8;
  unsigned short* lA1 = lA0 + 256 * 8;
  unsigned short* lB0 = lB + (size_t)(wv * 64) * 8;
  unsigned short* lB1 = lB0 + 256 * 8;

  f32x4 acc[4][4];
#pragma unroll
  for (int i = 0; i < 4; ++i)
#pragma unroll
    for (int j = 0; j < 4; ++j) acc[i][j] = (f32x4){0.f, 0.f, 0.f, 0.f};

  for (int k0 = 0; k0 < K; k0 += 32) {
    gld16(gA0 + k0, lA0);
    gld16(gA1 + k0, lA1);
    gld16(gB0 + k0, lB0);
    gld16(gB1 + k0, lB1);
    __syncthreads();
    short8 af[4], bfr[4];
#pragma unroll
    for (int i = 0; i < 4; ++i)
      af[i] = *(const short8*)&lA[(wm * 64 + i * 16 + lq) * 32 + quad * 8];
#pragma unroll
    for (int j = 0; j < 4; ++j)
      bfr[j] = *(const short8*)&lB[(wn * 64 + j * 16 + lq) * 32 + quad * 8];
#pragma unroll
    for (int i = 0; i < 4; ++i)
#pragma unroll
      for (int j = 0; j < 4; ++j)
        acc[i][j] = __builtin_amdgcn_mfma_f32_16x16x32_bf16(af[i], bfr[j],
                                                            acc[i][j], 0, 0, 0);
    __syncthreads();
  }

  const int n0 = nt * 128 + wn * 64;
  float bv4[4];
#pragma unroll
  for (int j = 0; j < 4; ++j) bv4[j] = bias[n0 + j * 16 + lq];

  const int tok0 = mt * 128 + wm * 64;
  const int b = tok0 >> 11;
  const int s0 = tok0 & (kS - 1);
  const int h = n0 >> 6;
  if (mode < 2) {
    unsigned short* o = (mode == 0) ? oq : okk;
    const float scl = (mode == 0) ? QSCALE : 1.0f;
#pragma unroll
    for (int i = 0; i < 4; ++i)
#pragma unroll
      for (int j = 0; j < 4; ++j) {
        const int d = j * 16 + lq;
#pragma unroll
        for (int r = 0; r < 4; ++r) {
          const int s = s0 + i * 16 + quad * 4 + r;
          o[((size_t)(b * kH + h) * kS + s) * kDH + d] =
              f2bf((acc[i][j][r] + bv4[j]) * scl);
        }
      }
  } else {
#pragma unroll
    for (int i = 0; i < 4; ++i)
#pragma unroll
      for (int j = 0; j < 4; ++j) {
        const int d = j * 16 + lq;
        union { unsigned short u[4]; uint2 v; } pk;
#pragma unroll
        for (int r = 0; r < 4; ++r) pk.u[r] = f2bf(acc[i][j][r] + bv4[j]);
        const int s = s0 + i * 16 + quad * 4;
        *(uint2*)(ov + ((size_t)(b * kH + h) * kDH + d) * kS + s) = pk.v;
      }
  }
}

// ---------------- out-proj GEMM: 128x64 tiles, fp32 out + bias -----------
__global__ __launch_bounds__(256) void gemm_out_kernel(
    const unsigned short* __restrict__ A, const unsigned short* __restrict__ Bt,
    const float* __restrict__ bo, float* __restrict__ of) {
  constexpr int K = 1024;
  const int mt = blockIdx.x, nt = blockIdx.y;
  const int tid = threadIdx.x;
  const int wv = tid >> 6, lane = tid & 63, lq = lane & 15, quad = lane >> 4;
  const int wm = wv >> 1, wn = wv & 1;

  __shared__ unsigned short lA[128 * 32];   // 8 KB
  __shared__ unsigned short lB[64 * 32];    // 4 KB

  const int c0 = wv * 64 + lane;
  const int c1 = c0 + 256;
  const unsigned short* gA0 = A + (size_t)(mt * 128 + (c0 >> 2)) * K + (c0 & 3) * 8;
  const unsigned short* gA1 = A + (size_t)(mt * 128 + (c1 >> 2)) * K + (c1 & 3) * 8;
  const unsigned short* gB0 = Bt + (size_t)(nt * 64 + (c0 >> 2)) * K + (c0 & 3) * 8;
  unsigned short* lA0 = lA + (size_t)(wv * 64) * 8;
  unsigned short* lA1 = lA0 + 256 * 8;
  unsigned short* lB0 = lB + (size_t)(wv * 64) * 8;

  f32x4 acc[4][2];
#pragma unroll
  for (int i = 0; i < 4; ++i)
#pragma unroll
    for (int j = 0; j < 2; ++j) acc[i][j] = (f32x4){0.f, 0.f, 0.f, 0.f};

  for (int k0 = 0; k0 < K; k0 += 32) {
    gld16(gA0 + k0, lA0);
    gld16(gA1 + k0, lA1);
    gld16(gB0 + k0, lB0);
    __syncthreads();
    short8 af[4], bfr[2];
#pragma unroll
    for (int i = 0; i < 4; ++i)
      af[i] = *(const short8*)&lA[(wm * 64 + i * 16 + lq) * 32 + quad * 8];
#pragma unroll
    for (int j = 0; j < 2; ++j)
      bfr[j] = *(const short8*)&lB[(wn * 32 + j * 16 + lq) * 32 + quad * 8];
#pragma unroll
    for (int i = 0; i < 4; ++i)
#pragma unroll
      for (int j = 0; j < 2; ++j)
        acc[i][j] = __builtin_amdgcn_mfma_f32_16x16x32_bf16(af[i], bfr[j],
                                                            acc[i][j], 0, 0, 0);
    __syncthreads();
  }

  const int n0 = nt * 64 + wn * 32;
  const int m0 = mt * 128 + wm * 64;
  float bv2[2];
#pragma unroll
  for (int j = 0; j < 2; ++j) bv2[j] = bo[n0 + j * 16 + lq];
#pragma unroll
  for (int i = 0; i < 4; ++i)
#pragma unroll
    for (int j = 0; j < 2; ++j)
#pragma unroll
      for (int r = 0; r < 4; ++r)
        of[(size_t)(m0 + i * 16 + quad * 4 + r) * kE + n0 + j * 16 + lq] =
            acc[i][j][r] + bv2[j];
}

// ---------------- bf16 MFMA flash attention, direct-global K/V -----------
// QT=128, 4 waves x 32 q-rows. B-fragments for QK and PV are loaded straight
// from global in MFMA layout (no Ks/Vt LDS, no barriers in the K-loop).
// Single-buffer register prefetch: next-K issued after QK consumes kb,
// next-V after PV consumes vb. Pb (P layout transform) is wave-private.
#define QT 128
#define KT 64
#define LDK 72
__global__ __launch_bounds__(256) void attn_mfma_kernel(
    const unsigned short* __restrict__ q, const unsigned short* __restrict__ k,
    const unsigned short* __restrict__ vt, unsigned short* __restrict__ cc) {
  const int bh = blockIdx.y;
  const int b = bh >> 4, h = bh & 15;
  const int tid = threadIdx.x;
  const int wv = tid >> 6;
  const int lane = tid & 63;
  const int lq = lane & 15;
  const int quad = lane >> 4;

  __shared__ unsigned short Pb[QT][LDK];   // 18 KB, wave-private rows

  const int q0 = blockIdx.x * QT;

  short8 qa[2][2];
#pragma unroll
  for (int mf = 0; mf < 2; ++mf) {
    const unsigned short* qbase =
        q + ((size_t)bh * kS + q0 + wv * 32 + mf * 16 + lq) * kDH;
    qa[mf][0] = *(const short8*)(qbase + quad * 8);
    qa[mf][1] = *(const short8*)(qbase + 32 + quad * 8);
  }

  f32x4 Oacc[2][4];
  f32x4 Osum[2];
#pragma unroll
  for (int mf = 0; mf < 2; ++mf) {
    Osum[mf] = (f32x4){0.f, 0.f, 0.f, 0.f};
#pragma unroll
    for (int dt = 0; dt < 4; ++dt) Oacc[mf][dt] = (f32x4){0.f, 0.f, 0.f, 0.f};
  }

  unsigned short ob[8];
#pragma unroll
  for (int i = 0; i < 8; ++i) ob[i] = 0x3F80;   // bf16 1.0
  const short8 ones = *(const short8*)ob;

  // per-lane fragment base pointers (MFMA B-layout, direct from global):
  // QK: kb[nt][half] = K[t0 + nt*16 + lq][half*32 + quad*8 ..+7]
  // PV: vb[dt][half] = vt[dt*16 + lq][t0 + half*32 + quad*8 ..+7]
  const unsigned short* kfp =
      k + (size_t)bh * kS * kDH + (size_t)lq * kDH + quad * 8;
  const unsigned short* vfp =
      vt + (size_t)bh * kDH * kS + (size_t)lq * kS + quad * 8;

  short8 kb[4][2], vb[4][2];
#pragma unroll
  for (int nt = 0; nt < 4; ++nt) {
    const unsigned short* p = kfp + (size_t)nt * 16 * kDH;
    kb[nt][0] = *(const short8*)p;
    kb[nt][1] = *(const short8*)(p + 32);
  }
#pragma unroll
  for (int dt = 0; dt < 4; ++dt) {
    const unsigned short* p = vfp + (size_t)dt * 16 * kS;
    vb[dt][0] = *(const short8*)p;
    vb[dt][1] = *(const short8*)(p + 32);
  }

  for (int t0 = 0; t0 < kS; t0 += KT) {
    // S = Q K^T from register frags
    f32x4 S[2][4];
#pragma unroll
    for (int nt = 0; nt < 4; ++nt)
#pragma unroll
      for (int mf = 0; mf < 2; ++mf) {
        f32x4 a = (f32x4){0.f, 0.f, 0.f, 0.f};
        a = __builtin_amdgcn_mfma_f32_16x16x32_bf16(qa[mf][0], kb[nt][0], a, 0, 0, 0);
        a = __builtin_amdgcn_mfma_f32_16x16x32_bf16(qa[mf][1], kb[nt][1], a, 0, 0, 0);
        S[mf][nt] = a;
      }

    // prefetch next K tile (kb regs free after the MFMAs above)
    if (t0 + KT < kS) {
      const unsigned short* kn = kfp + (size_t)(t0 + KT) * kDH;
#pragma unroll
      for (int nt = 0; nt < 4; ++nt) {
        const unsigned short* p = kn + (size_t)nt * 16 * kDH;
        kb[nt][0] = *(const short8*)p;
        kb[nt][1] = *(const short8*)(p + 32);
      }
    }

    // P = exp2(S) -> bf16 (half-up) -> wave-private Pb rows
#pragma unroll
    for (int mf = 0; mf < 2; ++mf)
#pragma unroll
      for (int nt = 0; nt < 4; ++nt)
#pragma unroll
        for (int r = 0; r < 4; ++r) {
          const float p = __builtin_amdgcn_exp2f(S[mf][nt][r]);
          union { float f; unsigned u; } x; x.f = p;
          Pb[wv * 32 + mf * 16 + quad * 4 + r][nt * 16 + lq] =
              (unsigned short)((x.u + 0x8000u) >> 16);
        }
    // intra-wave lgkmcnt ordering suffices (rows are wave-private)

    short8 pa[2][2];
#pragma unroll
    for (int mf = 0; mf < 2; ++mf) {
      pa[mf][0] = *(const short8*)&Pb[wv * 32 + mf * 16 + lq][quad * 8];
      pa[mf][1] = *(const short8*)&Pb[wv * 32 + mf * 16 + lq][32 + quad * 8];
    }

#pragma unroll
    for (int dt = 0; dt < 4; ++dt)
#pragma unroll
      for (int mf = 0; mf < 2; ++mf) {
        Oacc[mf][dt] =
            __builtin_amdgcn_mfma_f32_16x16x32_bf16(pa[mf][0], vb[dt][0], Oacc[mf][dt], 0, 0, 0);
        Oacc[mf][dt] =
            __builtin_amdgcn_mfma_f32_16x16x32_bf16(pa[mf][1], vb[dt][1], Oacc[mf][dt], 0, 0, 0);
      }
#pragma unroll
    for (int mf = 0; mf < 2; ++mf) {
      Osum[mf] = __builtin_amdgcn_mfma_f32_16x16x32_bf16(pa[mf][0], ones, Osum[mf], 0, 0, 0);
      Osum[mf] = __builtin_amdgcn_mfma_f32_16x16x32_bf16(pa[mf][1], ones, Osum[mf], 0, 0, 0);
    }

    // prefetch next V tile (vb regs free after the MFMAs above)
    if (t0 + KT < kS) {
      const unsigned short* vn = vfp + (t0 + KT);
#pragma unroll
      for (int dt = 0; dt < 4; ++dt) {
        const unsigned short* p = vn + (size_t)dt * 16 * kS;
        vb[dt][0] = *(const short8*)p;
        vb[dt][1] = *(const short8*)(p + 32);
      }
    }
  }

#pragma unroll
  for (int mf = 0; mf < 2; ++mf)
#pragma unroll
    for (int r = 0; r < 4; ++r) {
      const float inv = 1.0f / Osum[mf][r];
      const int qrow = q0 + wv * 32 + mf * 16 + quad * 4 + r;
      unsigned short* base = cc + ((size_t)b * kS + qrow) * kA + h * kDH;
#pragma unroll
      for (int dt = 0; dt < 4; ++dt)
        base[dt * 16 + lq] = f2bf(Oacc[mf][dt][r] * inv);
    }
}

}  // namespace

extern "C" void kernel_launch(void* const* d_in, const int* in_sizes, int n_in,
                              void* d_out, int out_size, void* d_ws, size_t ws_size,
                              hipStream_t stream) {
  const float* x  = (const float*)d_in[0];
  const float* Wq = (const float*)d_in[1];
  const float* bq = (const float*)d_in[2];
  const float* Wk = (const float*)d_in[3];
  const float* bk = (const float*)d_in[4];
  const float* Wv = (const float*)d_in[5];
  const float* bv = (const float*)d_in[6];
  const float* Wo = (const float*)d_in[7];
  const float* bo = (const float*)d_in[8];
  float* out = (float*)d_out;

  const size_t per = (size_t)kBn * kH * kS * kDH;  // 4 Mi elems
  unsigned short* xb  = (unsigned short*)d_ws;
  unsigned short* qb  = xb + per;
  unsigned short* kb  = qb + per;
  unsigned short* vtb = kb + per;
  unsigned short* cc  = vtb + per;
  unsigned short* Wt  = cc + per;          // 3 Mi
  unsigned short* Wot = Wt + 3 * (per / 4);

  cast_x_kernel<<<dim3(per / (256 * 8)), 256, 0, stream>>>(x, xb);
  cast_wqkv_kernel<<<dim3(16, 16, 3), 256, 0, stream>>>(Wq, Wk, Wv, Wt);
  cast_wo_kernel<<<dim3(16, 16), 256, 0, stream>>>(Wo, Wot);

  gemm_bf16_kernel<<<dim3(32, 8, 3), 256, 0, stream>>>(
      xb, Wt, bq, bk, bv, qb, kb, vtb);

  attn_mfma_kernel<<<dim3(kS / QT, kBn * kH), 256, 0, stream>>>(qb, kb, vtb, cc);

  gemm_out_kernel<<<dim3(32, 16), 256, 0, stream>>>(cc, Wot, bo, out);
}

// Round 12
// 203.263 us; speedup vs baseline: 1.2840x; 1.2840x over previous
//
#include <hip/hip_runtime.h>
#include <math.h>

// MultiHeadAttention: B=2,S=2048,E=1024,H=16,DH=64,A=1024. fp32 in/out.
// Round 12: exact R8 base (197.7us verified best; R11's direct-global frags
// broke coalescing and wave-sharing -> reverted). Attention now uses the
// 16x16x16 chaining identity: S^T = K.Q^T exits MFMA in exactly the B-operand
// layout PV needs (x16 only: C row=quad*4+r matches B k=quad*4+j), so the P
// LDS round-trip (32 b16 writes + 4 b128 reads/lane/tile) is deleted; P is
// exp2+packed in registers. K/V staging + reg prefetch + raw barriers as R8.
// __has_builtin-guarded; falls back to the R8 Pb path if x16 bf16 is absent.
// d_ws (bf16 elems): xb[4Mi] qb[4Mi] kb[4Mi] vtb[4Mi] cc[4Mi] Wt[3Mi] Wot[1Mi]

namespace {
constexpr int kBn = 2, kS = 2048, kE = 1024, kH = 16, kDH = 64, kA = 1024;

typedef __attribute__((ext_vector_type(8))) short short8;
typedef __attribute__((ext_vector_type(4))) short short4;
typedef __attribute__((ext_vector_type(4))) float f32x4;

#if __has_builtin(__builtin_amdgcn_mfma_f32_16x16x16_bf16_1k)
#define HAVE_MFMA16 1
#define MFMA16(a, b, c) __builtin_amdgcn_mfma_f32_16x16x16_bf16_1k(a, b, c, 0, 0, 0)
#elif __has_builtin(__builtin_amdgcn_mfma_f32_16x16x16_bf16)
#define HAVE_MFMA16 1
#define MFMA16(a, b, c) __builtin_amdgcn_mfma_f32_16x16x16_bf16(a, b, c, 0, 0, 0)
#else
#define HAVE_MFMA16 0
#endif

// q pre-scale: (1/sqrt(DH)) * log2(e) so attention uses raw v_exp_f32.
#define QSCALE 0.18033688011112042f

__device__ inline unsigned short f2bf(float f) {
  union { float f; unsigned u; } x; x.f = f;
  unsigned r = x.u + 0x7fffu + ((x.u >> 16) & 1u);   // RNE
  return (unsigned short)(r >> 16);
}

__device__ inline void gld16(const void* g, void* l) {
  __builtin_amdgcn_global_load_lds(
      (const __attribute__((address_space(1))) unsigned int*)g,
      (__attribute__((address_space(3))) unsigned int*)l, 16, 0, 0);
}

// Raw workgroup barrier: LDS ordering only (lgkmcnt), no vmcnt drain.
__device__ inline void lds_barrier() {
  asm volatile("s_waitcnt lgkmcnt(0)" ::: "memory");
  __builtin_amdgcn_s_barrier();
}

// ---------------- cast x: fp32 -> bf16, elementwise ----------------------
__global__ __launch_bounds__(256) void cast_x_kernel(
    const float* __restrict__ x, unsigned short* __restrict__ xb) {
  const int i = (blockIdx.x * 256 + threadIdx.x) * 8;
  float4 a = *(const float4*)(x + i);
  float4 b = *(const float4*)(x + i + 4);
  unsigned short t[8];
  t[0] = f2bf(a.x); t[1] = f2bf(a.y); t[2] = f2bf(a.z); t[3] = f2bf(a.w);
  t[4] = f2bf(b.x); t[5] = f2bf(b.y); t[6] = f2bf(b.z); t[7] = f2bf(b.w);
  *(short8*)(xb + i) = *(const short8*)t;
}

// ---------------- cast+transpose Wq/Wk/Wv: [H,E,DH] -> [sel][h*64+d][e] --
__global__ __launch_bounds__(256) void cast_wqkv_kernel(
    const float* __restrict__ Wq, const float* __restrict__ Wk,
    const float* __restrict__ Wv, unsigned short* __restrict__ Wt) {
  const int sel = blockIdx.z;
  const float* __restrict__ W = (sel == 0) ? Wq : (sel == 1) ? Wk : Wv;
  const int h = blockIdx.y;
  const int e0 = blockIdx.x * 64;
  const int tid = threadIdx.x;

  __shared__ float T[64][68];
  const int el = tid >> 2, dq = tid & 3;
  const float* src = W + ((size_t)h * kE + e0 + el) * kDH + dq * 16;
#pragma unroll
  for (int j = 0; j < 4; ++j)
    *(float4*)&T[el][dq * 16 + j * 4] = *(const float4*)(src + j * 4);
  __syncthreads();

  const int d = tid & 63, w = tid >> 6;
  unsigned short t[16];
#pragma unroll
  for (int j = 0; j < 16; ++j) t[j] = f2bf(T[w * 16 + j][d]);
  unsigned short* dst =
      Wt + (((size_t)sel << 20) | ((size_t)(h * 64 + d) << 10)) + e0 + w * 16;
  *(short8*)dst = *(const short8*)&t[0];
  *(short8*)(dst + 8) = *(const short8*)&t[8];
}

// ---------------- cast+transpose Wo: [A,E] -> [e][a] ---------------------
__global__ __launch_bounds__(256) void cast_wo_kernel(
    const float* __restrict__ Wo, unsigned short* __restrict__ Wot) {
  const int a0 = blockIdx.x * 64, e0 = blockIdx.y * 64;
  const int tid = threadIdx.x;

  __shared__ float T[64][68];
  const int al = tid >> 2, dq = tid & 3;
  const float* src = Wo + (size_t)(a0 + al) * kE + e0 + dq * 16;
#pragma unroll
  for (int j = 0; j < 4; ++j)
    *(float4*)&T[al][dq * 16 + j * 4] = *(const float4*)(src + j * 4);
  __syncthreads();

  const int e = tid & 63, w = tid >> 6;
  unsigned short t[16];
#pragma unroll
  for (int j = 0; j < 16; ++j) t[j] = f2bf(T[w * 16 + j][e]);
  unsigned short* dst = Wot + ((size_t)(e0 + e) << 10) + a0 + w * 16;
  *(short8*)dst = *(const short8*)&t[0];
  *(short8*)(dst + 8) = *(const short8*)&t[8];
}

// ---------------- QKV GEMM (modes 0/1/2 over blockIdx.z) -----------------
// m97 structure (global_load_lds + __syncthreads; proven best at 3 blk/CU).
__global__ __launch_bounds__(256) void gemm_bf16_kernel(
    const unsigned short* __restrict__ A, const unsigned short* __restrict__ Bt,
    const float* __restrict__ b0, const float* __restrict__ b1,
    const float* __restrict__ b2,
    unsigned short* __restrict__ oq, unsigned short* __restrict__ okk,
    unsigned short* __restrict__ ov) {
  constexpr int K = 1024;
  const int mode = (int)blockIdx.z;
  const unsigned short* Bm = Bt + ((size_t)blockIdx.z << 20);
  const float* bias = (mode == 1) ? b1 : (mode == 2) ? b2 : b0;

  const int mt = blockIdx.x, nt = blockIdx.y;
  const int tid = threadIdx.x;
  const int wv = tid >> 6, lane = tid & 63, lq = lane & 15, quad = lane >> 4;
  const int wm = wv >> 1, wn = wv & 1;

  __shared__ unsigned short lA[128 * 32];
  __shared__ unsigned short lB[128 * 32];

  const int c0 = wv * 64 + lane;
  const int c1 = c0 + 256;
  const unsigned short* gA0 = A + (size_t)(mt * 128 + (c0 >> 2)) * K + (c0 & 3) * 8;
  const unsigned short* gA1 = A + (size_t)(mt * 128 + (c1 >> 2)) * K + (c1 & 3) * 8;
  const unsigned short* gB0 = Bm + (size_t)(nt * 128 + (c0 >> 2)) * K + (c0 & 3) * 8;
  const unsigned short* gB1 = Bm + (size_t)(nt * 128 + (c1 >> 2)) * K + (c1 & 3) * 8;
  unsigned short* lA0 = lA + (size_t)(wv * 64) * 8;
  unsigned short* lA1 = lA0 + 256 * 8;
  unsigned short* lB0 = lB + (size_t)(wv * 64) * 8;
  unsigned short* lB1 = lB0 + 256 * 8;

  f32x4 acc[4][4];
#pragma unroll
  for (int i = 0; i < 4; ++i)
#pragma unroll
    for (int j = 0; j < 4; ++j) acc[i][j] = (f32x4){0.f, 0.f, 0.f, 0.f};

  for (int k0 = 0; k0 < K; k0 += 32) {
    gld16(gA0 + k0, lA0);
    gld16(gA1 + k0, lA1);
    gld16(gB0 + k0, lB0);
    gld16(gB1 + k0, lB1);
    __syncthreads();
    short8 af[4], bfr[4];
#pragma unroll
    for (int i = 0; i < 4; ++i)
      af[i] = *(const short8*)&lA[(wm * 64 + i * 16 + lq) * 32 + quad * 8];
#pragma unroll
    for (int j = 0; j < 4; ++j)
      bfr[j] = *(const short8*)&lB[(wn * 64 + j * 16 + lq) * 32 + quad * 8];
#pragma unroll
    for (int i = 0; i < 4; ++i)
#pragma unroll
      for (int j = 0; j < 4; ++j)
        acc[i][j] = __builtin_amdgcn_mfma_f32_16x16x32_bf16(af[i], bfr[j],
                                                            acc[i][j], 0, 0, 0);
    __syncthreads();
  }

  const int n0 = nt * 128 + wn * 64;
  float bv4[4];
#pragma unroll
  for (int j = 0; j < 4; ++j) bv4[j] = bias[n0 + j * 16 + lq];

  const int tok0 = mt * 128 + wm * 64;
  const int b = tok0 >> 11;
  const int s0 = tok0 & (kS - 1);
  const int h = n0 >> 6;
  if (mode < 2) {
    unsigned short* o = (mode == 0) ? oq : okk;
    const float scl = (mode == 0) ? QSCALE : 1.0f;
#pragma unroll
    for (int i = 0; i < 4; ++i)
#pragma unroll
      for (int j = 0; j < 4; ++j) {
        const int d = j * 16 + lq;
#pragma unroll
        for (int r = 0; r < 4; ++r) {
          const int s = s0 + i * 16 + quad * 4 + r;
          o[((size_t)(b * kH + h) * kS + s) * kDH + d] =
              f2bf((acc[i][j][r] + bv4[j]) * scl);
        }
      }
  } else {
#pragma unroll
    for (int i = 0; i < 4; ++i)
#pragma unroll
      for (int j = 0; j < 4; ++j) {
        const int d = j * 16 + lq;
        union { unsigned short u[4]; uint2 v; } pk;
#pragma unroll
        for (int r = 0; r < 4; ++r) pk.u[r] = f2bf(acc[i][j][r] + bv4[j]);
        const int s = s0 + i * 16 + quad * 4;
        *(uint2*)(ov + ((size_t)(b * kH + h) * kDH + d) * kS + s) = pk.v;
      }
  }
}

// ---------------- out-proj GEMM: 128x64 tiles, fp32 out + bias -----------
__global__ __launch_bounds__(256) void gemm_out_kernel(
    const unsigned short* __restrict__ A, const unsigned short* __restrict__ Bt,
    const float* __restrict__ bo, float* __restrict__ of) {
  constexpr int K = 1024;
  const int mt = blockIdx.x, nt = blockIdx.y;
  const int tid = threadIdx.x;
  const int wv = tid >> 6, lane = tid & 63, lq = lane & 15, quad = lane >> 4;
  const int wm = wv >> 1, wn = wv & 1;

  __shared__ unsigned short lA[128 * 32];   // 8 KB
  __shared__ unsigned short lB[64 * 32];    // 4 KB

  const int c0 = wv * 64 + lane;
  const int c1 = c0 + 256;
  const unsigned short* gA0 = A + (size_t)(mt * 128 + (c0 >> 2)) * K + (c0 & 3) * 8;
  const unsigned short* gA1 = A + (size_t)(mt * 128 + (c1 >> 2)) * K + (c1 & 3) * 8;
  const unsigned short* gB0 = Bt + (size_t)(nt * 64 + (c0 >> 2)) * K + (c0 & 3) * 8;
  unsigned short* lA0 = lA + (size_t)(wv * 64) * 8;
  unsigned short* lA1 = lA0 + 256 * 8;
  unsigned short* lB0 = lB + (size_t)(wv * 64) * 8;

  f32x4 acc[4][2];
#pragma unroll
  for (int i = 0; i < 4; ++i)
#pragma unroll
    for (int j = 0; j < 2; ++j) acc[i][j] = (f32x4){0.f, 0.f, 0.f, 0.f};

  for (int k0 = 0; k0 < K; k0 += 32) {
    gld16(gA0 + k0, lA0);
    gld16(gA1 + k0, lA1);
    gld16(gB0 + k0, lB0);
    __syncthreads();
    short8 af[4], bfr[2];
#pragma unroll
    for (int i = 0; i < 4; ++i)
      af[i] = *(const short8*)&lA[(wm * 64 + i * 16 + lq) * 32 + quad * 8];
#pragma unroll
    for (int j = 0; j < 2; ++j)
      bfr[j] = *(const short8*)&lB[(wn * 32 + j * 16 + lq) * 32 + quad * 8];
#pragma unroll
    for (int i = 0; i < 4; ++i)
#pragma unroll
      for (int j = 0; j < 2; ++j)
        acc[i][j] = __builtin_amdgcn_mfma_f32_16x16x32_bf16(af[i], bfr[j],
                                                            acc[i][j], 0, 0, 0);
    __syncthreads();
  }

  const int n0 = nt * 64 + wn * 32;
  const int m0 = mt * 128 + wm * 64;
  float bv2[2];
#pragma unroll
  for (int j = 0; j < 2; ++j) bv2[j] = bo[n0 + j * 16 + lq];
#pragma unroll
  for (int i = 0; i < 4; ++i)
#pragma unroll
    for (int j = 0; j < 2; ++j)
#pragma unroll
      for (int r = 0; r < 4; ++r)
        of[(size_t)(m0 + i * 16 + quad * 4 + r) * kE + n0 + j * 16 + lq] =
            acc[i][j][r] + bv2[j];
}

// ---------------- bf16 MFMA flash attention, QT=128 ----------------------
// HAVE_MFMA16: S^T = K.Q^T via 16x16x16; P stays in registers (no Pb LDS).
// Else: exact R8 path (Pb round-trip). Staging/prefetch/barriers = R8.
#define QT 128
#define KT 64
#define LDK 72
__global__ __launch_bounds__(256) void attn_mfma_kernel(
    const unsigned short* __restrict__ q, const unsigned short* __restrict__ k,
    const unsigned short* __restrict__ vt, unsigned short* __restrict__ cc) {
  const int bh = blockIdx.y;
  const int b = bh >> 4, h = bh & 15;
  const int tid = threadIdx.x;
  const int wv = tid >> 6;
  const int lane = tid & 63;
  const int lq = lane & 15;
  const int quad = lane >> 4;

  __shared__ unsigned short Ks[KT][LDK];   // [t][d]   9 KB
  __shared__ unsigned short Vt[kDH][LDK];  // [d][t]   9 KB
#if !HAVE_MFMA16
  __shared__ unsigned short Pb[QT][LDK];   // fallback only
#endif

  const int q0 = blockIdx.x * QT;

  const unsigned short* kg = k + (size_t)bh * kS * kDH;
  const unsigned short* vg = vt + (size_t)bh * kDH * kS;

  const int sr = tid >> 3;
  const int sc = (tid & 7) << 3;

  short8 rk0 = *(const short8*)(kg + (size_t)sr * kDH + sc);
  short8 rk1 = *(const short8*)(kg + (size_t)(sr + 32) * kDH + sc);
  short8 rv0 = *(const short8*)(vg + (size_t)sr * kS + sc);
  short8 rv1 = *(const short8*)(vg + (size_t)(sr + 32) * kS + sc);

#if HAVE_MFMA16
  // Q as x16 B-operands: qb16[mf][c] = q[mf*16+lq][c*16+quad*4 ..+3]
  short4 qb16[2][4];
#pragma unroll
  for (int mf = 0; mf < 2; ++mf) {
    const unsigned short* qbase =
        q + ((size_t)bh * kS + q0 + wv * 32 + mf * 16 + lq) * kDH;
#pragma unroll
    for (int c = 0; c < 4; ++c)
      qb16[mf][c] = *(const short4*)(qbase + c * 16 + quad * 4);
  }

  unsigned short o4[4];
#pragma unroll
  for (int i = 0; i < 4; ++i) o4[i] = 0x3F80;    // bf16 1.0
  const short4 ones4 = *(const short4*)o4;

  f32x4 OaccT[4][2];                             // O^T: [dt][mf]
  f32x4 Osum[2];
#pragma unroll
  for (int mf = 0; mf < 2; ++mf) {
    Osum[mf] = (f32x4){0.f, 0.f, 0.f, 0.f};
#pragma unroll
    for (int dt = 0; dt < 4; ++dt) OaccT[dt][mf] = (f32x4){0.f, 0.f, 0.f, 0.f};
  }

  for (int t0 = 0; t0 < kS; t0 += KT) {
    lds_barrier();
    *(short8*)&Ks[sr][sc]      = rk0;
    *(short8*)&Ks[sr + 32][sc] = rk1;
    *(short8*)&Vt[sr][sc]      = rv0;
    *(short8*)&Vt[sr + 32][sc] = rv1;
    if (t0 + KT < kS) {
      const int tn = t0 + KT;
      rk0 = *(const short8*)(kg + (size_t)(tn + sr) * kDH + sc);
      rk1 = *(const short8*)(kg + (size_t)(tn + sr + 32) * kDH + sc);
      rv0 = *(const short8*)(vg + (size_t)sr * kS + tn + sc);
      rv1 = *(const short8*)(vg + (size_t)(sr + 32) * kS + tn + sc);
    }
    lds_barrier();

    // S^T[t][m] = K.Q^T : A=K rows (x16 A-layout), B=Q (x16 B-layout)
    f32x4 ST[4][2];
#pragma unroll
    for (int tt = 0; tt < 4; ++tt) {
      short4 ak[4];
#pragma unroll
      for (int c = 0; c < 4; ++c)
        ak[c] = *(const short4*)&Ks[tt * 16 + lq][c * 16 + quad * 4];
#pragma unroll
      for (int mf = 0; mf < 2; ++mf) {
        f32x4 a = (f32x4){0.f, 0.f, 0.f, 0.f};
#pragma unroll
        for (int c = 0; c < 4; ++c) a = MFMA16(ak[c], qb16[mf][c], a);
        ST[tt][mf] = a;
      }
    }

    // P^T = exp2(S^T) packed in-register: C row=quad*4+r == B k=quad*4+j
    short4 pp[4][2];
#pragma unroll
    for (int tt = 0; tt < 4; ++tt)
#pragma unroll
      for (int mf = 0; mf < 2; ++mf) {
        union { unsigned short u[4]; short4 v; } pk;
#pragma unroll
        for (int r = 0; r < 4; ++r) {
          const float p = __builtin_amdgcn_exp2f(ST[tt][mf][r]);
          union { float f; unsigned u; } x; x.f = p;
          pk.u[r] = (unsigned short)((x.u + 0x8000u) >> 16);
        }
        pp[tt][mf] = pk.v;
      }

    // denominators: ones.P^T (all C rows identical)
#pragma unroll
    for (int mf = 0; mf < 2; ++mf)
#pragma unroll
      for (int tt = 0; tt < 4; ++tt)
        Osum[mf] = MFMA16(ones4, pp[tt][mf], Osum[mf]);

    // O^T += V^T.P^T
#pragma unroll
    for (int dt = 0; dt < 4; ++dt) {
      short4 av[4];
#pragma unroll
      for (int tt = 0; tt < 4; ++tt)
        av[tt] = *(const short4*)&Vt[dt * 16 + lq][tt * 16 + quad * 4];
#pragma unroll
      for (int mf = 0; mf < 2; ++mf)
#pragma unroll
        for (int tt = 0; tt < 4; ++tt)
          OaccT[dt][mf] = MFMA16(av[tt], pp[tt][mf], OaccT[dt][mf]);
    }
  }

  // epilogue: O^T C-layout gives 4 consecutive d per lane -> 8B stores
#pragma unroll
  for (int mf = 0; mf < 2; ++mf) {
    const float inv = 1.0f / Osum[mf][0];
    const int qrow = q0 + wv * 32 + mf * 16 + lq;
    unsigned short* base = cc + ((size_t)b * kS + qrow) * kA + h * kDH;
#pragma unroll
    for (int dt = 0; dt < 4; ++dt) {
      union { unsigned short u[4]; uint2 v; } o;
#pragma unroll
      for (int r = 0; r < 4; ++r) o.u[r] = f2bf(OaccT[dt][mf][r] * inv);
      *(uint2*)(base + dt * 16 + quad * 4) = o.v;
    }
  }
#else
  // ---------------- fallback: exact R8 path ----------------
  short8 qa[2][2];
#pragma unroll
  for (int mf = 0; mf < 2; ++mf) {
    const unsigned short* qbase =
        q + ((size_t)bh * kS + q0 + wv * 32 + mf * 16 + lq) * kDH;
    qa[mf][0] = *(const short8*)(qbase + quad * 8);
    qa[mf][1] = *(const short8*)(qbase + 32 + quad * 8);
  }

  f32x4 Oacc[2][4];
  f32x4 Osum[2];
#pragma unroll
  for (int mf = 0; mf < 2; ++mf) {
    Osum[mf] = (f32x4){0.f, 0.f, 0.f, 0.f};
#pragma unroll
    for (int dt = 0; dt < 4; ++dt) Oacc[mf][dt] = (f32x4){0.f, 0.f, 0.f, 0.f};
  }

  unsigned short ob[8];
#pragma unroll
  for (int i = 0; i < 8; ++i) ob[i] = 0x3F80;
  const short8 ones = *(const short8*)ob;

  for (int t0 = 0; t0 < kS; t0 += KT) {
    lds_barrier();
    *(short8*)&Ks[sr][sc]      = rk0;
    *(short8*)&Ks[sr + 32][sc] = rk1;
    *(short8*)&Vt[sr][sc]      = rv0;
    *(short8*)&Vt[sr + 32][sc] = rv1;
    if (t0 + KT < kS) {
      const int tn = t0 + KT;
      rk0 = *(const short8*)(kg + (size_t)(tn + sr) * kDH + sc);
      rk1 = *(const short8*)(kg + (size_t)(tn + sr + 32) * kDH + sc);
      rv0 = *(const short8*)(vg + (size_t)sr * kS + tn + sc);
      rv1 = *(const short8*)(vg + (size_t)(sr + 32) * kS + tn + sc);
    }
    lds_barrier();

    f32x4 S[2][4];
#pragma unroll
    for (int nt = 0; nt < 4; ++nt) {
      short8 kb0 = *(const short8*)&Ks[nt * 16 + lq][quad * 8];
      short8 kb1 = *(const short8*)&Ks[nt * 16 + lq][32 + quad * 8];
#pragma unroll
      for (int mf = 0; mf < 2; ++mf) {
        f32x4 a = (f32x4){0.f, 0.f, 0.f, 0.f};
        a = __builtin_amdgcn_mfma_f32_16x16x32_bf16(qa[mf][0], kb0, a, 0, 0, 0);
        a = __builtin_amdgcn_mfma_f32_16x16x32_bf16(qa[mf][1], kb1, a, 0, 0, 0);
        S[mf][nt] = a;
      }
    }

#pragma unroll
    for (int mf = 0; mf < 2; ++mf)
#pragma unroll
      for (int nt = 0; nt < 4; ++nt)
#pragma unroll
        for (int r = 0; r < 4; ++r) {
          const float p = __builtin_amdgcn_exp2f(S[mf][nt][r]);
          union { float f; unsigned u; } x; x.f = p;
          Pb[wv * 32 + mf * 16 + quad * 4 + r][nt * 16 + lq] =
              (unsigned short)((x.u + 0x8000u) >> 16);
        }

    short8 pa[2][2];
#pragma unroll
    for (int mf = 0; mf < 2; ++mf) {
      pa[mf][0] = *(const short8*)&Pb[wv * 32 + mf * 16 + lq][quad * 8];
      pa[mf][1] = *(const short8*)&Pb[wv * 32 + mf * 16 + lq][32 + quad * 8];
    }

#pragma unroll
    for (int dt = 0; dt < 4; ++dt) {
      short8 vb0 = *(const short8*)&Vt[dt * 16 + lq][quad * 8];
      short8 vb1 = *(const short8*)&Vt[dt * 16 + lq][32 + quad * 8];
#pragma unroll
      for (int mf = 0; mf < 2; ++mf) {
        Oacc[mf][dt] =
            __builtin_amdgcn_mfma_f32_16x16x32_bf16(pa[mf][0], vb0, Oacc[mf][dt], 0, 0, 0);
        Oacc[mf][dt] =
            __builtin_amdgcn_mfma_f32_16x16x32_bf16(pa[mf][1], vb1, Oacc[mf][dt], 0, 0, 0);
      }
    }
#pragma unroll
    for (int mf = 0; mf < 2; ++mf) {
      Osum[mf] = __builtin_amdgcn_mfma_f32_16x16x32_bf16(pa[mf][0], ones, Osum[mf], 0, 0, 0);
      Osum[mf] = __builtin_amdgcn_mfma_f32_16x16x32_bf16(pa[mf][1], ones, Osum[mf], 0, 0, 0);
    }
  }

#pragma unroll
  for (int mf = 0; mf < 2; ++mf)
#pragma unroll
    for (int r = 0; r < 4; ++r) {
      const float inv = 1.0f / Osum[mf][r];
      const int qrow = q0 + wv * 32 + mf * 16 + quad * 4 + r;
      unsigned short* base = cc + ((size_t)b * kS + qrow) * kA + h * kDH;
#pragma unroll
      for (int dt = 0; dt < 4; ++dt)
        base[dt * 16 + lq] = f2bf(Oacc[mf][dt][r] * inv);
    }
#endif
}

}  // namespace

extern "C" void kernel_launch(void* const* d_in, const int* in_sizes, int n_in,
                              void* d_out, int out_size, void* d_ws, size_t ws_size,
                              hipStream_t stream) {
  const float* x  = (const float*)d_in[0];
  const float* Wq = (const float*)d_in[1];
  const float* bq = (const float*)d_in[2];
  const float* Wk = (const float*)d_in[3];
  const float* bk = (const float*)d_in[4];
  const float* Wv = (const float*)d_in[5];
  const float* bv = (const float*)d_in[6];
  const float* Wo = (const float*)d_in[7];
  const float* bo = (const float*)d_in[8];
  float* out = (float*)d_out;

  const size_t per = (size_t)kBn * kH * kS * kDH;  // 4 Mi elems
  unsigned short* xb  = (unsigned short*)d_ws;
  unsigned short* qb  = xb + per;
  unsigned short* kb  = qb + per;
  unsigned short* vtb = kb + per;
  unsigned short* cc  = vtb + per;
  unsigned short* Wt  = cc + per;          // 3 Mi
  unsigned short* Wot = Wt + 3 * (per / 4);

  cast_x_kernel<<<dim3(per / (256 * 8)), 256, 0, stream>>>(x, xb);
  cast_wqkv_kernel<<<dim3(16, 16, 3), 256, 0, stream>>>(Wq, Wk, Wv, Wt);
  cast_wo_kernel<<<dim3(16, 16), 256, 0, stream>>>(Wo, Wot);

  gemm_bf16_kernel<<<dim3(32, 8, 3), 256, 0, stream>>>(
      xb, Wt, bq, bk, bv, qb, kb, vtb);

  attn_mfma_kernel<<<dim3(kS / QT, kBn * kH), 256, 0, stream>>>(qb, kb, vtb, cc);

  gemm_out_kernel<<<dim3(32, 16), 256, 0, stream>>>(cc, Wot, bo, out);
}

// Round 13
// 203.032 us; speedup vs baseline: 1.2854x; 1.0011x over previous
//
#include <hip/hip_runtime.h>
#include <math.h>

// MultiHeadAttention: B=2,S=2048,E=1024,H=16,DH=64,A=1024. fp32 in/out.
// Round 13: R12's x16 chaining idea with the CORRECT builtin name
// (__builtin_amdgcn_mfma_f32_16x16x16bf16_1k -- no underscore before bf16;
// R12's guard failed silently and measured the R8 fallback, proven by
// LDS_Block_Size=36864). S^T = K.Q^T exits x16 MFMA in exactly the B-operand
// layout PV needs (C row-span 4 == x16 k-span 4) -> P LDS round-trip deleted.
// Also: 3 prep kernels fused into one (range-dispatched 1D grid).
// GEMMs = R8 m97 structure (proven best). Fallback to R8 attn if no builtin.
// d_ws (bf16 elems): xb[4Mi] qb[4Mi] kb[4Mi] vtb[4Mi] cc[4Mi] Wt[3Mi] Wot[1Mi]

namespace {
constexpr int kBn = 2, kS = 2048, kE = 1024, kH = 16, kDH = 64, kA = 1024;

typedef __attribute__((ext_vector_type(8))) short short8;
typedef __attribute__((ext_vector_type(4))) short short4;
typedef __attribute__((ext_vector_type(4))) float f32x4;

#if __has_builtin(__builtin_amdgcn_mfma_f32_16x16x16bf16_1k)
#define HAVE_MFMA16 1
#define MFMA16(a, b, c) __builtin_amdgcn_mfma_f32_16x16x16bf16_1k(a, b, c, 0, 0, 0)
#elif __has_builtin(__builtin_amdgcn_mfma_f32_16x16x16_bf16_1k)
#define HAVE_MFMA16 1
#define MFMA16(a, b, c) __builtin_amdgcn_mfma_f32_16x16x16_bf16_1k(a, b, c, 0, 0, 0)
#else
#define HAVE_MFMA16 0
#endif

// q pre-scale: (1/sqrt(DH)) * log2(e) so attention uses raw v_exp_f32.
#define QSCALE 0.18033688011112042f

__device__ inline unsigned short f2bf(float f) {
  union { float f; unsigned u; } x; x.f = f;
  unsigned r = x.u + 0x7fffu + ((x.u >> 16) & 1u);   // RNE
  return (unsigned short)(r >> 16);
}

__device__ inline void gld16(const void* g, void* l) {
  __builtin_amdgcn_global_load_lds(
      (const __attribute__((address_space(1))) unsigned int*)g,
      (__attribute__((address_space(3))) unsigned int*)l, 16, 0, 0);
}

// Raw workgroup barrier: LDS ordering only (lgkmcnt), no vmcnt drain.
__device__ inline void lds_barrier() {
  asm volatile("s_waitcnt lgkmcnt(0)" ::: "memory");
  __builtin_amdgcn_s_barrier();
}

// ---------------- fused prep: cast x + cast/transpose all weights --------
// grid 3072x256: [0,2048) cast_x; [2048,2816) Wq/Wk/Wv; [2816,3072) Wo.
__global__ __launch_bounds__(256) void prep_kernel(
    const float* __restrict__ x,
    const float* __restrict__ Wq, const float* __restrict__ Wk,
    const float* __restrict__ Wv, const float* __restrict__ Wo,
    unsigned short* __restrict__ xb, unsigned short* __restrict__ Wt,
    unsigned short* __restrict__ Wot) {
  const int bid = blockIdx.x;
  const int tid = threadIdx.x;

  if (bid < 2048) {
    const int i = (bid * 256 + tid) * 8;
    float4 a = *(const float4*)(x + i);
    float4 b = *(const float4*)(x + i + 4);
    unsigned short t[8];
    t[0] = f2bf(a.x); t[1] = f2bf(a.y); t[2] = f2bf(a.z); t[3] = f2bf(a.w);
    t[4] = f2bf(b.x); t[5] = f2bf(b.y); t[6] = f2bf(b.z); t[7] = f2bf(b.w);
    *(short8*)(xb + i) = *(const short8*)t;
    return;
  }

  __shared__ float T[64][68];
  if (bid < 2816) {
    const int idx = bid - 2048;
    const int sel = idx >> 8;
    const int h = (idx >> 4) & 15;
    const int e0 = (idx & 15) * 64;
    const float* __restrict__ W = (sel == 0) ? Wq : (sel == 1) ? Wk : Wv;
    const int el = tid >> 2, dq = tid & 3;
    const float* src = W + ((size_t)h * kE + e0 + el) * kDH + dq * 16;
#pragma unroll
    for (int j = 0; j < 4; ++j)
      *(float4*)&T[el][dq * 16 + j * 4] = *(const float4*)(src + j * 4);
    __syncthreads();

    const int d = tid & 63, w = tid >> 6;
    unsigned short t[16];
#pragma unroll
    for (int j = 0; j < 16; ++j) t[j] = f2bf(T[w * 16 + j][d]);
    unsigned short* dst =
        Wt + (((size_t)sel << 20) | ((size_t)(h * 64 + d) << 10)) + e0 + w * 16;
    *(short8*)dst = *(const short8*)&t[0];
    *(short8*)(dst + 8) = *(const short8*)&t[8];
  } else {
    const int idx = bid - 2816;
    const int a0 = (idx & 15) * 64, e0 = ((idx >> 4) & 15) * 64;
    const int al = tid >> 2, dq = tid & 3;
    const float* src = Wo + (size_t)(a0 + al) * kE + e0 + dq * 16;
#pragma unroll
    for (int j = 0; j < 4; ++j)
      *(float4*)&T[al][dq * 16 + j * 4] = *(const float4*)(src + j * 4);
    __syncthreads();

    const int e = tid & 63, w = tid >> 6;
    unsigned short t[16];
#pragma unroll
    for (int j = 0; j < 16; ++j) t[j] = f2bf(T[w * 16 + j][e]);
    unsigned short* dst = Wot + ((size_t)(e0 + e) << 10) + a0 + w * 16;
    *(short8*)dst = *(const short8*)&t[0];
    *(short8*)(dst + 8) = *(const short8*)&t[8];
  }
}

// ---------------- QKV GEMM (modes 0/1/2 over blockIdx.z) -----------------
// m97 structure (global_load_lds + __syncthreads; proven best at 3 blk/CU).
__global__ __launch_bounds__(256) void gemm_bf16_kernel(
    const unsigned short* __restrict__ A, const unsigned short* __restrict__ Bt,
    const float* __restrict__ b0, const float* __restrict__ b1,
    const float* __restrict__ b2,
    unsigned short* __restrict__ oq, unsigned short* __restrict__ okk,
    unsigned short* __restrict__ ov) {
  constexpr int K = 1024;
  const int mode = (int)blockIdx.z;
  const unsigned short* Bm = Bt + ((size_t)blockIdx.z << 20);
  const float* bias = (mode == 1) ? b1 : (mode == 2) ? b2 : b0;

  const int mt = blockIdx.x, nt = blockIdx.y;
  const int tid = threadIdx.x;
  const int wv = tid >> 6, lane = tid & 63, lq = lane & 15, quad = lane >> 4;
  const int wm = wv >> 1, wn = wv & 1;

  __shared__ unsigned short lA[128 * 32];
  __shared__ unsigned short lB[128 * 32];

  const int c0 = wv * 64 + lane;
  const int c1 = c0 + 256;
  const unsigned short* gA0 = A + (size_t)(mt * 128 + (c0 >> 2)) * K + (c0 & 3) * 8;
  const unsigned short* gA1 = A + (size_t)(mt * 128 + (c1 >> 2)) * K + (c1 & 3) * 8;
  const unsigned short* gB0 = Bm + (size_t)(nt * 128 + (c0 >> 2)) * K + (c0 & 3) * 8;
  const unsigned short* gB1 = Bm + (size_t)(nt * 128 + (c1 >> 2)) * K + (c1 & 3) * 8;
  unsigned short* lA0 = lA + (size_t)(wv * 64) * 8;
  unsigned short* lA1 = lA0 + 256 * 8;
  unsigned short* lB0 = lB + (size_t)(wv * 64) * 8;
  unsigned short* lB1 = lB0 + 256 * 8;

  f32x4 acc[4][4];
#pragma unroll
  for (int i = 0; i < 4; ++i)
#pragma unroll
    for (int j = 0; j < 4; ++j) acc[i][j] = (f32x4){0.f, 0.f, 0.f, 0.f};

  for (int k0 = 0; k0 < K; k0 += 32) {
    gld16(gA0 + k0, lA0);
    gld16(gA1 + k0, lA1);
    gld16(gB0 + k0, lB0);
    gld16(gB1 + k0, lB1);
    __syncthreads();
    short8 af[4], bfr[4];
#pragma unroll
    for (int i = 0; i < 4; ++i)
      af[i] = *(const short8*)&lA[(wm * 64 + i * 16 + lq) * 32 + quad * 8];
#pragma unroll
    for (int j = 0; j < 4; ++j)
      bfr[j] = *(const short8*)&lB[(wn * 64 + j * 16 + lq) * 32 + quad * 8];
#pragma unroll
    for (int i = 0; i < 4; ++i)
#pragma unroll
      for (int j = 0; j < 4; ++j)
        acc[i][j] = __builtin_amdgcn_mfma_f32_16x16x32_bf16(af[i], bfr[j],
                                                            acc[i][j], 0, 0, 0);
    __syncthreads();
  }

  const int n0 = nt * 128 + wn * 64;
  float bv4[4];
#pragma unroll
  for (int j = 0; j < 4; ++j) bv4[j] = bias[n0 + j * 16 + lq];

  const int tok0 = mt * 128 + wm * 64;
  const int b = tok0 >> 11;
  const int s0 = tok0 & (kS - 1);
  const int h = n0 >> 6;
  if (mode < 2) {
    unsigned short* o = (mode == 0) ? oq : okk;
    const float scl = (mode == 0) ? QSCALE : 1.0f;
#pragma unroll
    for (int i = 0; i < 4; ++i)
#pragma unroll
      for (int j = 0; j < 4; ++j) {
        const int d = j * 16 + lq;
#pragma unroll
        for (int r = 0; r < 4; ++r) {
          const int s = s0 + i * 16 + quad * 4 + r;
          o[((size_t)(b * kH + h) * kS + s) * kDH + d] =
              f2bf((acc[i][j][r] + bv4[j]) * scl);
        }
      }
  } else {
#pragma unroll
    for (int i = 0; i < 4; ++i)
#pragma unroll
      for (int j = 0; j < 4; ++j) {
        const int d = j * 16 + lq;
        union { unsigned short u[4]; uint2 v; } pk;
#pragma unroll
        for (int r = 0; r < 4; ++r) pk.u[r] = f2bf(acc[i][j][r] + bv4[j]);
        const int s = s0 + i * 16 + quad * 4;
        *(uint2*)(ov + ((size_t)(b * kH + h) * kDH + d) * kS + s) = pk.v;
      }
  }
}

// ---------------- out-proj GEMM: 128x64 tiles, fp32 out + bias -----------
__global__ __launch_bounds__(256) void gemm_out_kernel(
    const unsigned short* __restrict__ A, const unsigned short* __restrict__ Bt,
    const float* __restrict__ bo, float* __restrict__ of) {
  constexpr int K = 1024;
  const int mt = blockIdx.x, nt = blockIdx.y;
  const int tid = threadIdx.x;
  const int wv = tid >> 6, lane = tid & 63, lq = lane & 15, quad = lane >> 4;
  const int wm = wv >> 1, wn = wv & 1;

  __shared__ unsigned short lA[128 * 32];   // 8 KB
  __shared__ unsigned short lB[64 * 32];    // 4 KB

  const int c0 = wv * 64 + lane;
  const int c1 = c0 + 256;
  const unsigned short* gA0 = A + (size_t)(mt * 128 + (c0 >> 2)) * K + (c0 & 3) * 8;
  const unsigned short* gA1 = A + (size_t)(mt * 128 + (c1 >> 2)) * K + (c1 & 3) * 8;
  const unsigned short* gB0 = Bt + (size_t)(nt * 64 + (c0 >> 2)) * K + (c0 & 3) * 8;
  unsigned short* lA0 = lA + (size_t)(wv * 64) * 8;
  unsigned short* lA1 = lA0 + 256 * 8;
  unsigned short* lB0 = lB + (size_t)(wv * 64) * 8;

  f32x4 acc[4][2];
#pragma unroll
  for (int i = 0; i < 4; ++i)
#pragma unroll
    for (int j = 0; j < 2; ++j) acc[i][j] = (f32x4){0.f, 0.f, 0.f, 0.f};

  for (int k0 = 0; k0 < K; k0 += 32) {
    gld16(gA0 + k0, lA0);
    gld16(gA1 + k0, lA1);
    gld16(gB0 + k0, lB0);
    __syncthreads();
    short8 af[4], bfr[2];
#pragma unroll
    for (int i = 0; i < 4; ++i)
      af[i] = *(const short8*)&lA[(wm * 64 + i * 16 + lq) * 32 + quad * 8];
#pragma unroll
    for (int j = 0; j < 2; ++j)
      bfr[j] = *(const short8*)&lB[(wn * 32 + j * 16 + lq) * 32 + quad * 8];
#pragma unroll
    for (int i = 0; i < 4; ++i)
#pragma unroll
      for (int j = 0; j < 2; ++j)
        acc[i][j] = __builtin_amdgcn_mfma_f32_16x16x32_bf16(af[i], bfr[j],
                                                            acc[i][j], 0, 0, 0);
    __syncthreads();
  }

  const int n0 = nt * 64 + wn * 32;
  const int m0 = mt * 128 + wm * 64;
  float bv2[2];
#pragma unroll
  for (int j = 0; j < 2; ++j) bv2[j] = bo[n0 + j * 16 + lq];
#pragma unroll
  for (int i = 0; i < 4; ++i)
#pragma unroll
    for (int j = 0; j < 2; ++j)
#pragma unroll
      for (int r = 0; r < 4; ++r)
        of[(size_t)(m0 + i * 16 + quad * 4 + r) * kE + n0 + j * 16 + lq] =
            acc[i][j][r] + bv2[j];
}

// ---------------- bf16 MFMA flash attention, QT=128 ----------------------
// HAVE_MFMA16: S^T = K.Q^T via 16x16x16; P stays in registers (no Pb LDS).
// Else: exact R8 path. Staging/prefetch/raw barriers identical to R8.
#define QT 128
#define KT 64
#define LDK 72
__global__ __launch_bounds__(256) void attn_mfma_kernel(
    const unsigned short* __restrict__ q, const unsigned short* __restrict__ k,
    const unsigned short* __restrict__ vt, unsigned short* __restrict__ cc) {
  const int bh = blockIdx.y;
  const int b = bh >> 4, h = bh & 15;
  const int tid = threadIdx.x;
  const int wv = tid >> 6;
  const int lane = tid & 63;
  const int lq = lane & 15;
  const int quad = lane >> 4;

  __shared__ unsigned short Ks[KT][LDK];   // [t][d]   9 KB
  __shared__ unsigned short Vt[kDH][LDK];  // [d][t]   9 KB
#if !HAVE_MFMA16
  __shared__ unsigned short Pb[QT][LDK];   // fallback only
#endif

  const int q0 = blockIdx.x * QT;

  const unsigned short* kg = k + (size_t)bh * kS * kDH;
  const unsigned short* vg = vt + (size_t)bh * kDH * kS;

  const int sr = tid >> 3;
  const int sc = (tid & 7) << 3;

  short8 rk0 = *(const short8*)(kg + (size_t)sr * kDH + sc);
  short8 rk1 = *(const short8*)(kg + (size_t)(sr + 32) * kDH + sc);
  short8 rv0 = *(const short8*)(vg + (size_t)sr * kS + sc);
  short8 rv1 = *(const short8*)(vg + (size_t)(sr + 32) * kS + sc);

#if HAVE_MFMA16
  // Q as x16 B-operands: qb16[mf][c] = q[mf*16+lq][c*16+quad*4 ..+3]
  short4 qb16[2][4];
#pragma unroll
  for (int mf = 0; mf < 2; ++mf) {
    const unsigned short* qbase =
        q + ((size_t)bh * kS + q0 + wv * 32 + mf * 16 + lq) * kDH;
#pragma unroll
    for (int c = 0; c < 4; ++c)
      qb16[mf][c] = *(const short4*)(qbase + c * 16 + quad * 4);
  }

  unsigned short o4[4];
#pragma unroll
  for (int i = 0; i < 4; ++i) o4[i] = 0x3F80;    // bf16 1.0
  const short4 ones4 = *(const short4*)o4;

  f32x4 OaccT[4][2];                             // O^T: [dt][mf]
  f32x4 Osum[2];
#pragma unroll
  for (int mf = 0; mf < 2; ++mf) {
    Osum[mf] = (f32x4){0.f, 0.f, 0.f, 0.f};
#pragma unroll
    for (int dt = 0; dt < 4; ++dt) OaccT[dt][mf] = (f32x4){0.f, 0.f, 0.f, 0.f};
  }

  for (int t0 = 0; t0 < kS; t0 += KT) {
    lds_barrier();
    *(short8*)&Ks[sr][sc]      = rk0;
    *(short8*)&Ks[sr + 32][sc] = rk1;
    *(short8*)&Vt[sr][sc]      = rv0;
    *(short8*)&Vt[sr + 32][sc] = rv1;
    if (t0 + KT < kS) {
      const int tn = t0 + KT;
      rk0 = *(const short8*)(kg + (size_t)(tn + sr) * kDH + sc);
      rk1 = *(const short8*)(kg + (size_t)(tn + sr + 32) * kDH + sc);
      rv0 = *(const short8*)(vg + (size_t)sr * kS + tn + sc);
      rv1 = *(const short8*)(vg + (size_t)(sr + 32) * kS + tn + sc);
    }
    lds_barrier();

    // S^T[t][m] = K.Q^T : A=K rows (x16 A-layout), B=Q (x16 B-layout)
    f32x4 ST[4][2];
#pragma unroll
    for (int tt = 0; tt < 4; ++tt) {
      short4 ak[4];
#pragma unroll
      for (int c = 0; c < 4; ++c)
        ak[c] = *(const short4*)&Ks[tt * 16 + lq][c * 16 + quad * 4];
#pragma unroll
      for (int mf = 0; mf < 2; ++mf) {
        f32x4 a = (f32x4){0.f, 0.f, 0.f, 0.f};
#pragma unroll
        for (int c = 0; c < 4; ++c) a = MFMA16(ak[c], qb16[mf][c], a);
        ST[tt][mf] = a;
      }
    }

    // P^T = exp2(S^T) packed in-register: C row=quad*4+r == B k=quad*4+j
    short4 pp[4][2];
#pragma unroll
    for (int tt = 0; tt < 4; ++tt)
#pragma unroll
      for (int mf = 0; mf < 2; ++mf) {
        union { unsigned short u[4]; short4 v; } pk;
#pragma unroll
        for (int r = 0; r < 4; ++r) {
          const float p = __builtin_amdgcn_exp2f(ST[tt][mf][r]);
          union { float f; unsigned u; } x; x.f = p;
          pk.u[r] = (unsigned short)((x.u + 0x8000u) >> 16);
        }
        pp[tt][mf] = pk.v;
      }

    // denominators: ones.P^T (all C rows identical)
#pragma unroll
    for (int mf = 0; mf < 2; ++mf)
#pragma unroll
      for (int tt = 0; tt < 4; ++tt)
        Osum[mf] = MFMA16(ones4, pp[tt][mf], Osum[mf]);

    // O^T += V^T.P^T
#pragma unroll
    for (int dt = 0; dt < 4; ++dt) {
      short4 av[4];
#pragma unroll
      for (int tt = 0; tt < 4; ++tt)
        av[tt] = *(const short4*)&Vt[dt * 16 + lq][tt * 16 + quad * 4];
#pragma unroll
      for (int mf = 0; mf < 2; ++mf)
#pragma unroll
        for (int tt = 0; tt < 4; ++tt)
          OaccT[dt][mf] = MFMA16(av[tt], pp[tt][mf], OaccT[dt][mf]);
    }
  }

  // epilogue: O^T C-layout gives 4 consecutive d per lane -> 8B stores
#pragma unroll
  for (int mf = 0; mf < 2; ++mf) {
    const float inv = 1.0f / Osum[mf][0];
    const int qrow = q0 + wv * 32 + mf * 16 + lq;
    unsigned short* base = cc + ((size_t)b * kS + qrow) * kA + h * kDH;
#pragma unroll
    for (int dt = 0; dt < 4; ++dt) {
      union { unsigned short u[4]; uint2 v; } o;
#pragma unroll
      for (int r = 0; r < 4; ++r) o.u[r] = f2bf(OaccT[dt][mf][r] * inv);
      *(uint2*)(base + dt * 16 + quad * 4) = o.v;
    }
  }
#else
  // ---------------- fallback: exact R8 path ----------------
  short8 qa[2][2];
#pragma unroll
  for (int mf = 0; mf < 2; ++mf) {
    const unsigned short* qbase =
        q + ((size_t)bh * kS + q0 + wv * 32 + mf * 16 + lq) * kDH;
    qa[mf][0] = *(const short8*)(qbase + quad * 8);
    qa[mf][1] = *(const short8*)(qbase + 32 + quad * 8);
  }

  f32x4 Oacc[2][4];
  f32x4 Osum[2];
#pragma unroll
  for (int mf = 0; mf < 2; ++mf) {
    Osum[mf] = (f32x4){0.f, 0.f, 0.f, 0.f};
#pragma unroll
    for (int dt = 0; dt < 4; ++dt) Oacc[mf][dt] = (f32x4){0.f, 0.f, 0.f, 0.f};
  }

  unsigned short ob[8];
#pragma unroll
  for (int i = 0; i < 8; ++i) ob[i] = 0x3F80;
  const short8 ones = *(const short8*)ob;

  for (int t0 = 0; t0 < kS; t0 += KT) {
    lds_barrier();
    *(short8*)&Ks[sr][sc]      = rk0;
    *(short8*)&Ks[sr + 32][sc] = rk1;
    *(short8*)&Vt[sr][sc]      = rv0;
    *(short8*)&Vt[sr + 32][sc] = rv1;
    if (t0 + KT < kS) {
      const int tn = t0 + KT;
      rk0 = *(const short8*)(kg + (size_t)(tn + sr) * kDH + sc);
      rk1 = *(const short8*)(kg + (size_t)(tn + sr + 32) * kDH + sc);
      rv0 = *(const short8*)(vg + (size_t)sr * kS + tn + sc);
      rv1 = *(const short8*)(vg + (size_t)(sr + 32) * kS + tn + sc);
    }
    lds_barrier();

    f32x4 S[2][4];
#pragma unroll
    for (int nt = 0; nt < 4; ++nt) {
      short8 kb0 = *(const short8*)&Ks[nt * 16 + lq][quad * 8];
      short8 kb1 = *(const short8*)&Ks[nt * 16 + lq][32 + quad * 8];
#pragma unroll
      for (int mf = 0; mf < 2; ++mf) {
        f32x4 a = (f32x4){0.f, 0.f, 0.f, 0.f};
        a = __builtin_amdgcn_mfma_f32_16x16x32_bf16(qa[mf][0], kb0, a, 0, 0, 0);
        a = __builtin_amdgcn_mfma_f32_16x16x32_bf16(qa[mf][1], kb1, a, 0, 0, 0);
        S[mf][nt] = a;
      }
    }

#pragma unroll
    for (int mf = 0; mf < 2; ++mf)
#pragma unroll
      for (int nt = 0; nt < 4; ++nt)
#pragma unroll
        for (int r = 0; r < 4; ++r) {
          const float p = __builtin_amdgcn_exp2f(S[mf][nt][r]);
          union { float f; unsigned u; } x; x.f = p;
          Pb[wv * 32 + mf * 16 + quad * 4 + r][nt * 16 + lq] =
              (unsigned short)((x.u + 0x8000u) >> 16);
        }

    short8 pa[2][2];
#pragma unroll
    for (int mf = 0; mf < 2; ++mf) {
      pa[mf][0] = *(const short8*)&Pb[wv * 32 + mf * 16 + lq][quad * 8];
      pa[mf][1] = *(const short8*)&Pb[wv * 32 + mf * 16 + lq][32 + quad * 8];
    }

#pragma unroll
    for (int dt = 0; dt < 4; ++dt) {
      short8 vb0 = *(const short8*)&Vt[dt * 16 + lq][quad * 8];
      short8 vb1 = *(const short8*)&Vt[dt * 16 + lq][32 + quad * 8];
#pragma unroll
      for (int mf = 0; mf < 2; ++mf) {
        Oacc[mf][dt] =
            __builtin_amdgcn_mfma_f32_16x16x32_bf16(pa[mf][0], vb0, Oacc[mf][dt], 0, 0, 0);
        Oacc[mf][dt] =
            __builtin_amdgcn_mfma_f32_16x16x32_bf16(pa[mf][1], vb1, Oacc[mf][dt], 0, 0, 0);
      }
    }
#pragma unroll
    for (int mf = 0; mf < 2; ++mf) {
      Osum[mf] = __builtin_amdgcn_mfma_f32_16x16x32_bf16(pa[mf][0], ones, Osum[mf], 0, 0, 0);
      Osum[mf] = __builtin_amdgcn_mfma_f32_16x16x32_bf16(pa[mf][1], ones, Osum[mf], 0, 0, 0);
    }
  }

#pragma unroll
  for (int mf = 0; mf < 2; ++mf)
#pragma unroll
    for (int r = 0; r < 4; ++r) {
      const float inv = 1.0f / Osum[mf][r];
      const int qrow = q0 + wv * 32 + mf * 16 + quad * 4 + r;
      unsigned short* base = cc + ((size_t)b * kS + qrow) * kA + h * kDH;
#pragma unroll
      for (int dt = 0; dt < 4; ++dt)
        base[dt * 16 + lq] = f2bf(Oacc[mf][dt][r] * inv);
    }
#endif
}

}  // namespace

extern "C" void kernel_launch(void* const* d_in, const int* in_sizes, int n_in,
                              void* d_out, int out_size, void* d_ws, size_t ws_size,
                              hipStream_t stream) {
  const float* x  = (const float*)d_in[0];
  const float* Wq = (const float*)d_in[1];
  const float* bq = (const float*)d_in[2];
  const float* Wk = (const float*)d_in[3];
  const float* bk = (const float*)d_in[4];
  const float* Wv = (const float*)d_in[5];
  const float* bv = (const float*)d_in[6];
  const float* Wo = (const float*)d_in[7];
  const float* bo = (const float*)d_in[8];
  float* out = (float*)d_out;

  const size_t per = (size_t)kBn * kH * kS * kDH;  // 4 Mi elems
  unsigned short* xb  = (unsigned short*)d_ws;
  unsigned short* qb  = xb + per;
  unsigned short* kb  = qb + per;
  unsigned short* vtb = kb + per;
  unsigned short* cc  = vtb + per;
  unsigned short* Wt  = cc + per;          // 3 Mi
  unsigned short* Wot = Wt + 3 * (per / 4);

  prep_kernel<<<dim3(3072), 256, 0, stream>>>(x, Wq, Wk, Wv, Wo, xb, Wt, Wot);

  gemm_bf16_kernel<<<dim3(32, 8, 3), 256, 0, stream>>>(
      xb, Wt, bq, bk, bv, qb, kb, vtb);

  attn_mfma_kernel<<<dim3(kS / QT, kBn * kH), 256, 0, stream>>>(qb, kb, vtb, cc);

  gemm_out_kernel<<<dim3(32, 16), 256, 0, stream>>>(cc, Wot, bo, out);
}